// Round 1
// baseline (491.041 us; speedup 1.0000x reference)
//
#include <hip/hip_runtime.h>
#include <cmath>

#define NN 100000
#define EE 1600000

using bf16x8 = __attribute__((ext_vector_type(8))) __bf16;
using f32x4  = __attribute__((ext_vector_type(4))) float;

__device__ __forceinline__ unsigned short f2bf(float f) {
  __bf16 b = (__bf16)f;
  return __builtin_bit_cast(unsigned short, b);
}
__device__ __forceinline__ float bf2f(unsigned short u) {
  __bf16 b = __builtin_bit_cast(__bf16, u);
  return (float)b;
}
__device__ __forceinline__ float sigmoidf_(float v) {
  return 1.0f / (1.0f + __expf(-v));
}
__device__ __forceinline__ bf16x8 cvt8(float4 a, float4 b) {
  bf16x8 r;
  r[0]=(__bf16)a.x; r[1]=(__bf16)a.y; r[2]=(__bf16)a.z; r[3]=(__bf16)a.w;
  r[4]=(__bf16)b.x; r[5]=(__bf16)b.y; r[6]=(__bf16)b.z; r[7]=(__bf16)b.w;
  return r;
}

// ---------------- K1: xs = x @ W_gat (bf16 MFMA), plus a_src/a_dst dots ----
__global__ __launch_bounds__(256) void k_proj(
    const float* __restrict__ x, const float* __restrict__ Wg,
    const float* __restrict__ att_s, const float* __restrict__ att_d,
    unsigned short* __restrict__ xs16, float* __restrict__ a_src,
    float* __restrict__ a_dst)
{
  const int lane = threadIdx.x & 63;
  const int wave = threadIdx.x >> 6;
  const int tile = blockIdx.x * 4 + wave;     // 16-row tile of x
  if (tile >= NN / 16) return;
  const int m = lane & 15, quad = lane >> 4;

  // B-frag: B[n=h=lane&15][k=quad*8+j] = Wg[k][h]  (Wg is [64][64] k-major)
  bf16x8 bfrag[4][2];
  #pragma unroll
  for (int nt = 0; nt < 4; ++nt)
    #pragma unroll
    for (int kf = 0; kf < 2; ++kf)
      #pragma unroll
      for (int j = 0; j < 8; ++j)
        bfrag[nt][kf][j] = (__bf16)Wg[(kf*32 + quad*8 + j)*64 + nt*16 + m];

  const int row = tile*16 + m;
  bf16x8 afrag[2];
  #pragma unroll
  for (int kf = 0; kf < 2; ++kf) {
    const float4* p = (const float4*)(x + row*64 + kf*32 + quad*8);
    afrag[kf] = cvt8(p[0], p[1]);
  }

  f32x4 acc[4];
  #pragma unroll
  for (int nt = 0; nt < 4; ++nt) acc[nt] = f32x4{0.f, 0.f, 0.f, 0.f};
  #pragma unroll
  for (int nt = 0; nt < 4; ++nt)
    #pragma unroll
    for (int kf = 0; kf < 2; ++kf)
      acc[nt] = __builtin_amdgcn_mfma_f32_16x16x32_bf16(
          afrag[kf], bfrag[nt][kf], acc[nt], 0, 0, 0);

  // D layout: col = lane&15 (within 16-wide ntile), row = quad*4 + r
  float ss[4] = {0.f,0.f,0.f,0.f}, sd[4] = {0.f,0.f,0.f,0.f};
  #pragma unroll
  for (int nt = 0; nt < 4; ++nt) {
    const float av = att_s[nt*16 + m], dv = att_d[nt*16 + m];
    #pragma unroll
    for (int r = 0; r < 4; ++r) {
      const float v = acc[nt][r];
      xs16[(tile*16 + quad*4 + r)*64 + nt*16 + m] = f2bf(v);
      ss[r] += v * av;
      sd[r] += v * dv;
    }
  }
  // reduce over the 16 n-lanes within each quad
  #pragma unroll
  for (int off = 1; off < 16; off <<= 1) {
    #pragma unroll
    for (int r = 0; r < 4; ++r) {
      ss[r] += __shfl_xor(ss[r], off);
      sd[r] += __shfl_xor(sd[r], off);
    }
  }
  if (m == 0) {
    #pragma unroll
    for (int r = 0; r < 4; ++r) {
      a_src[tile*16 + quad*4 + r] = ss[r];
      a_dst[tile*16 + quad*4 + r] = sd[r];
    }
  }
}

// ---------------- CSR build ------------------------------------------------
__global__ __launch_bounds__(256) void k_deg(const int* __restrict__ ei,
                                             int* __restrict__ deg) {
  const int e = blockIdx.x*256 + threadIdx.x;
  if (e < EE) atomicAdd(&deg[ei[EE + e]], 1);
}

__global__ __launch_bounds__(256) void k_scan_a(const int* __restrict__ deg,
                                                int* __restrict__ bsums) {
  __shared__ int sm[256];
  const int t = threadIdx.x;
  const int base = blockIdx.x*1024 + t*4;
  int s = 0;
  #pragma unroll
  for (int j = 0; j < 4; ++j) { int i = base + j; if (i < NN) s += deg[i]; }
  sm[t] = s; __syncthreads();
  for (int off = 128; off > 0; off >>= 1) {
    if (t < off) sm[t] += sm[t + off];
    __syncthreads();
  }
  if (t == 0) bsums[blockIdx.x] = sm[0];
}

__global__ __launch_bounds__(128) void k_scan_b(const int* __restrict__ bsums,
                                                int* __restrict__ boffs, int nb) {
  __shared__ int sm[128];
  const int t = threadIdx.x;
  const int v = (t < nb) ? bsums[t] : 0;
  sm[t] = v; __syncthreads();
  int acc = v;
  for (int off = 1; off < 128; off <<= 1) {
    const int xv = (t >= off) ? sm[t - off] : 0;
    __syncthreads();
    acc += xv; sm[t] = acc;
    __syncthreads();
  }
  boffs[t] = acc - v;   // exclusive
}

__global__ __launch_bounds__(256) void k_scan_c(const int* __restrict__ deg,
                                                const int* __restrict__ boffs,
                                                int* __restrict__ rowptr) {
  __shared__ int sm[256];
  const int t = threadIdx.x;
  const int base = blockIdx.x*1024 + t*4;
  int v[4]; int s = 0;
  #pragma unroll
  for (int j = 0; j < 4; ++j) {
    const int i = base + j;
    v[j] = (i < NN) ? deg[i] : 0;
    s += v[j];
  }
  sm[t] = s; __syncthreads();
  int acc = s;
  for (int off = 1; off < 256; off <<= 1) {
    const int xv = (t >= off) ? sm[t - off] : 0;
    __syncthreads();
    acc += xv; sm[t] = acc;
    __syncthreads();
  }
  int run = acc - s + boffs[blockIdx.x];
  #pragma unroll
  for (int j = 0; j < 4; ++j) {
    const int i = base + j;
    if (i < NN) rowptr[i] = run;
    run += v[j];
  }
}

__global__ __launch_bounds__(256) void k_scatter(const int* __restrict__ ei,
    const int* __restrict__ rowptr, int* __restrict__ fill,
    int* __restrict__ col) {
  const int e = blockIdx.x*256 + threadIdx.x;
  if (e < EE) {
    const int d = ei[EE + e];
    const int pos = atomicAdd(&fill[d], 1);
    col[rowptr[d] + pos] = ei[e];
  }
}

// ---------------- K5: per-node softmax + aggregation (wave per node) -------
__global__ __launch_bounds__(256) void k_agg(
    const int* __restrict__ rowptr, const int* __restrict__ deg,
    const int* __restrict__ col, const float* __restrict__ a_src,
    const float* __restrict__ a_dst, const unsigned short* __restrict__ xs16,
    const float* __restrict__ bias, unsigned short* __restrict__ xb16)
{
  const int lane = threadIdx.x & 63;
  const int node = (blockIdx.x * 256 + threadIdx.x) >> 6;
  if (node >= NN) return;
  const int base = rowptr[node];
  const int dg = deg[node];
  const float ad = a_dst[node];

  // pass 1: max of leaky_relu(a_src[src] + a_dst[node])
  float mx = -1e30f;
  for (int e = lane; e < dg; e += 64) {
    float ev = a_src[col[base + e]] + ad;
    ev = (ev >= 0.f) ? ev : 0.2f * ev;
    mx = fmaxf(mx, ev);
  }
  #pragma unroll
  for (int off = 32; off; off >>= 1) mx = fmaxf(mx, __shfl_xor(mx, off));

  // pass 2: sum exp
  float zs = 0.f;
  for (int e = lane; e < dg; e += 64) {
    float ev = a_src[col[base + e]] + ad;
    ev = (ev >= 0.f) ? ev : 0.2f * ev;
    zs += __expf(ev - mx);
  }
  #pragma unroll
  for (int off = 32; off; off >>= 1) zs += __shfl_xor(zs, off);
  const float invz = 1.f / (zs + 1e-16f);

  // pass 3: acc[lane] = sum_e alpha_e * xs[src_e][lane]
  float acc = 0.f;
  for (int e0 = 0; e0 < dg; e0 += 64) {
    const int e = e0 + lane;
    float alpha = 0.f; int s = 0;
    if (e < dg) {
      s = col[base + e];
      float ev = a_src[s] + ad;
      ev = (ev >= 0.f) ? ev : 0.2f * ev;
      alpha = __expf(ev - mx) * invz;
    }
    const int cnt = min(64, dg - e0);
    for (int t = 0; t < cnt; ++t) {
      const float a_t = __shfl(alpha, t);
      const int   s_t = __shfl(s, t);
      acc += a_t * bf2f(xs16[s_t*64 + lane]);
    }
  }
  xb16[node*64 + lane] = f2bf(tanhf(acc + bias[lane]));
}

// ---------------- K6: LSTM gates via bf16 MFMA + fused elementwise ---------
__global__ __launch_bounds__(256) void k_lstm(
    const unsigned short* __restrict__ xb16, const float* __restrict__ h0,
    const float* __restrict__ c0, const float* __restrict__ Wih,
    const float* __restrict__ Whh, float* __restrict__ out)
{
  __shared__ float gates[16][256];
  const int lane = threadIdx.x & 63;
  const int wave = threadIdx.x >> 6;     // gate quarter
  const int m = lane & 15, quad = lane >> 4;

  // B-frags: Wcat[g][k], g = wave*64 + nt*16 + m, k = kf*32 + quad*8 + j
  bf16x8 bfrag[4][4];
  #pragma unroll
  for (int nt = 0; nt < 4; ++nt) {
    const int g = wave*64 + nt*16 + m;
    #pragma unroll
    for (int kf = 0; kf < 4; ++kf) {
      const float* sp = (kf < 2) ? (Wih + g*64 + kf*32 + quad*8)
                                 : (Whh + g*64 + (kf - 2)*32 + quad*8);
      bfrag[nt][kf] = cvt8(*(const float4*)sp, *(const float4*)(sp + 4));
    }
  }

  for (int tile = blockIdx.x; tile < NN/16; tile += gridDim.x) {
    const int nodeb = tile * 16;
    bf16x8 afrag[4];
    afrag[0] = *(const bf16x8*)(xb16 + (nodeb + m)*64 + quad*8);
    afrag[1] = *(const bf16x8*)(xb16 + (nodeb + m)*64 + 32 + quad*8);
    #pragma unroll
    for (int kf = 2; kf < 4; ++kf) {
      const float* sp = h0 + (nodeb + m)*64 + (kf - 2)*32 + quad*8;
      afrag[kf] = cvt8(*(const float4*)sp, *(const float4*)(sp + 4));
    }

    f32x4 acc[4];
    #pragma unroll
    for (int nt = 0; nt < 4; ++nt) acc[nt] = f32x4{0.f, 0.f, 0.f, 0.f};
    #pragma unroll
    for (int nt = 0; nt < 4; ++nt)
      #pragma unroll
      for (int kf = 0; kf < 4; ++kf)
        acc[nt] = __builtin_amdgcn_mfma_f32_16x16x32_bf16(
            afrag[kf], bfrag[nt][kf], acc[nt], 0, 0, 0);

    #pragma unroll
    for (int nt = 0; nt < 4; ++nt)
      #pragma unroll
      for (int r = 0; r < 4; ++r)
        gates[quad*4 + r][wave*64 + nt*16 + m] = acc[nt][r];
    __syncthreads();

    const int hcol = threadIdx.x & 63;
    #pragma unroll
    for (int it = 0; it < 4; ++it) {
      const int nl = (threadIdx.x >> 6) + it*4;
      const int node = nodeb + nl;
      const float gi = gates[nl][hcol];
      const float gf = gates[nl][64 + hcol];
      const float gg = gates[nl][128 + hcol];
      const float go = gates[nl][192 + hcol];
      const float cv = c0[node*64 + hcol];
      const float c1 = sigmoidf_(gf)*cv + sigmoidf_(gi)*tanhf(gg);
      const float h1 = sigmoidf_(go)*tanhf(c1);
      out[node*64 + hcol] = h1;
      out[NN*64 + node*64 + hcol] = h1;
      out[2*NN*64 + node*64 + hcol] = c1;
    }
    __syncthreads();
  }
}

// ---------------- launch ---------------------------------------------------
extern "C" void kernel_launch(void* const* d_in, const int* in_sizes, int n_in,
                              void* d_out, int out_size, void* d_ws, size_t ws_size,
                              hipStream_t stream) {
  const float* x    = (const float*)d_in[0];
  const int*   ei   = (const int*)d_in[1];
  const float* h    = (const float*)d_in[2];
  const float* c    = (const float*)d_in[3];
  const float* Wg   = (const float*)d_in[4];
  const float* atts = (const float*)d_in[5];
  const float* attd = (const float*)d_in[6];
  const float* bg   = (const float*)d_in[7];
  const float* Wih  = (const float*)d_in[8];
  const float* Whh  = (const float*)d_in[9];
  float* out = (float*)d_out;

  char* w = (char*)d_ws;
  unsigned short* xs16 = (unsigned short*)w; w += (size_t)NN*64*2;
  unsigned short* xb16 = (unsigned short*)w; w += (size_t)NN*64*2;
  float* a_src = (float*)w; w += (size_t)NN*4;
  float* a_dst = (float*)w; w += (size_t)NN*4;
  int* deg    = (int*)w; w += (size_t)NN*4;
  int* fill   = (int*)w; w += (size_t)NN*4;   // adjacent to deg: one memset
  int* rowptr = (int*)w; w += (size_t)NN*4;
  int* col    = (int*)w; w += (size_t)EE*4;
  int* bsums  = (int*)w; w += 128*4;
  int* boffs  = (int*)w; w += 128*4;

  hipMemsetAsync(deg, 0, (size_t)2*NN*4, stream);   // deg + fill

  k_proj   <<<(NN/16 + 3)/4, 256, 0, stream>>>(x, Wg, atts, attd, xs16, a_src, a_dst);
  k_deg    <<<EE/256, 256, 0, stream>>>(ei, deg);
  k_scan_a <<<(NN + 1023)/1024, 256, 0, stream>>>(deg, bsums);
  k_scan_b <<<1, 128, 0, stream>>>(bsums, boffs, (NN + 1023)/1024);
  k_scan_c <<<(NN + 1023)/1024, 256, 0, stream>>>(deg, boffs, rowptr);
  k_scatter<<<EE/256, 256, 0, stream>>>(ei, rowptr, fill, col);
  k_agg    <<<NN/4, 256, 0, stream>>>(rowptr, deg, col, a_src, a_dst, xs16, bg, xb16);
  k_lstm   <<<625, 256, 0, stream>>>(xb16, h, c, Wih, Whh, out);
}

// Round 2
// 442.055 us; speedup vs baseline: 1.1108x; 1.1108x over previous
//
#include <hip/hip_runtime.h>
#include <cmath>

#define NN 100000
#define EE 1600000

using bf16x8 = __attribute__((ext_vector_type(8))) __bf16;
using f32x4  = __attribute__((ext_vector_type(4))) float;

__device__ __forceinline__ unsigned short f2bf(float f) {
  __bf16 b = (__bf16)f;
  return __builtin_bit_cast(unsigned short, b);
}
__device__ __forceinline__ float bflo(unsigned int u) {  // low bf16 of a dword
  return __uint_as_float(u << 16);
}
__device__ __forceinline__ float bfhi(unsigned int u) {  // high bf16 of a dword
  return __uint_as_float(u & 0xffff0000u);
}
__device__ __forceinline__ float sigmoidf_(float v) {
  return 1.0f / (1.0f + __expf(-v));
}
__device__ __forceinline__ bf16x8 cvt8(float4 a, float4 b) {
  bf16x8 r;
  r[0]=(__bf16)a.x; r[1]=(__bf16)a.y; r[2]=(__bf16)a.z; r[3]=(__bf16)a.w;
  r[4]=(__bf16)b.x; r[5]=(__bf16)b.y; r[6]=(__bf16)b.z; r[7]=(__bf16)b.w;
  return r;
}

// ---------------- K1: xs = x @ W_gat (bf16 MFMA), plus a_src/a_dst dots ----
__global__ __launch_bounds__(256) void k_proj(
    const float* __restrict__ x, const float* __restrict__ Wg,
    const float* __restrict__ att_s, const float* __restrict__ att_d,
    unsigned short* __restrict__ xs16, float* __restrict__ a_src,
    float* __restrict__ a_dst)
{
  const int lane = threadIdx.x & 63;
  const int wave = threadIdx.x >> 6;
  const int tile = blockIdx.x * 4 + wave;     // 16-row tile of x
  if (tile >= NN / 16) return;
  const int m = lane & 15, quad = lane >> 4;

  // B-frag: B[n=h=lane&15][k=quad*8+j] = Wg[k][h]  (Wg is [64][64] k-major)
  bf16x8 bfrag[4][2];
  #pragma unroll
  for (int nt = 0; nt < 4; ++nt)
    #pragma unroll
    for (int kf = 0; kf < 2; ++kf)
      #pragma unroll
      for (int j = 0; j < 8; ++j)
        bfrag[nt][kf][j] = (__bf16)Wg[(kf*32 + quad*8 + j)*64 + nt*16 + m];

  const int row = tile*16 + m;
  bf16x8 afrag[2];
  #pragma unroll
  for (int kf = 0; kf < 2; ++kf) {
    const float4* p = (const float4*)(x + row*64 + kf*32 + quad*8);
    afrag[kf] = cvt8(p[0], p[1]);
  }

  f32x4 acc[4];
  #pragma unroll
  for (int nt = 0; nt < 4; ++nt) acc[nt] = f32x4{0.f, 0.f, 0.f, 0.f};
  #pragma unroll
  for (int nt = 0; nt < 4; ++nt)
    #pragma unroll
    for (int kf = 0; kf < 2; ++kf)
      acc[nt] = __builtin_amdgcn_mfma_f32_16x16x32_bf16(
          afrag[kf], bfrag[nt][kf], acc[nt], 0, 0, 0);

  // D layout: col = lane&15 (within 16-wide ntile), row = quad*4 + r
  float ss[4] = {0.f,0.f,0.f,0.f}, sd[4] = {0.f,0.f,0.f,0.f};
  #pragma unroll
  for (int nt = 0; nt < 4; ++nt) {
    const float av = att_s[nt*16 + m], dv = att_d[nt*16 + m];
    #pragma unroll
    for (int r = 0; r < 4; ++r) {
      const float v = acc[nt][r];
      xs16[(tile*16 + quad*4 + r)*64 + nt*16 + m] = f2bf(v);
      ss[r] += v * av;
      sd[r] += v * dv;
    }
  }
  // reduce over the 16 n-lanes within each quad
  #pragma unroll
  for (int off = 1; off < 16; off <<= 1) {
    #pragma unroll
    for (int r = 0; r < 4; ++r) {
      ss[r] += __shfl_xor(ss[r], off);
      sd[r] += __shfl_xor(sd[r], off);
    }
  }
  if (m == 0) {
    #pragma unroll
    for (int r = 0; r < 4; ++r) {
      a_src[tile*16 + quad*4 + r] = ss[r];
      a_dst[tile*16 + quad*4 + r] = sd[r];
    }
  }
}

// ---------------- CSR build ------------------------------------------------
__global__ __launch_bounds__(256) void k_deg(const int* __restrict__ ei,
                                             int* __restrict__ deg) {
  const int e = blockIdx.x*256 + threadIdx.x;
  if (e < EE) atomicAdd(&deg[ei[EE + e]], 1);
}

__global__ __launch_bounds__(256) void k_scan_a(const int* __restrict__ deg,
                                                int* __restrict__ bsums) {
  __shared__ int sm[256];
  const int t = threadIdx.x;
  const int base = blockIdx.x*1024 + t*4;
  int s = 0;
  #pragma unroll
  for (int j = 0; j < 4; ++j) { int i = base + j; if (i < NN) s += deg[i]; }
  sm[t] = s; __syncthreads();
  for (int off = 128; off > 0; off >>= 1) {
    if (t < off) sm[t] += sm[t + off];
    __syncthreads();
  }
  if (t == 0) bsums[blockIdx.x] = sm[0];
}

__global__ __launch_bounds__(128) void k_scan_b(const int* __restrict__ bsums,
                                                int* __restrict__ boffs, int nb) {
  __shared__ int sm[128];
  const int t = threadIdx.x;
  const int v = (t < nb) ? bsums[t] : 0;
  sm[t] = v; __syncthreads();
  int acc = v;
  for (int off = 1; off < 128; off <<= 1) {
    const int xv = (t >= off) ? sm[t - off] : 0;
    __syncthreads();
    acc += xv; sm[t] = acc;
    __syncthreads();
  }
  boffs[t] = acc - v;   // exclusive
}

__global__ __launch_bounds__(256) void k_scan_c(const int* __restrict__ deg,
                                                const int* __restrict__ boffs,
                                                int* __restrict__ rowptr) {
  __shared__ int sm[256];
  const int t = threadIdx.x;
  const int base = blockIdx.x*1024 + t*4;
  int v[4]; int s = 0;
  #pragma unroll
  for (int j = 0; j < 4; ++j) {
    const int i = base + j;
    v[j] = (i < NN) ? deg[i] : 0;
    s += v[j];
  }
  sm[t] = s; __syncthreads();
  int acc = s;
  for (int off = 1; off < 256; off <<= 1) {
    const int xv = (t >= off) ? sm[t - off] : 0;
    __syncthreads();
    acc += xv; sm[t] = acc;
    __syncthreads();
  }
  int run = acc - s + boffs[blockIdx.x];
  #pragma unroll
  for (int j = 0; j < 4; ++j) {
    const int i = base + j;
    if (i < NN) rowptr[i] = run;
    run += v[j];
  }
}

// K4: scatter edges into CSR slots, fused with softmax numerator p = exp(e).
// (max-subtraction dropped: alpha = p/sum(p) is shift-invariant; e is O(±6).)
__global__ __launch_bounds__(256) void k_scatter(const int* __restrict__ ei,
    const float* __restrict__ a_src, const float* __restrict__ a_dst,
    const int* __restrict__ rowptr, int* __restrict__ fill,
    uint2* __restrict__ spcsr) {
  const int e = blockIdx.x*256 + threadIdx.x;
  if (e >= EE) return;
  const int s = ei[e];
  const int d = ei[EE + e];
  float ev = a_src[s] + a_dst[d];
  ev = (ev >= 0.f) ? ev : 0.2f * ev;
  const float p = __expf(ev);
  const int pos = atomicAdd(&fill[d], 1);
  spcsr[rowptr[d] + pos] = make_uint2((unsigned)s, __float_as_uint(p));
}

// ---------------- K5: per-node aggregation (wave per node, 4 grp x 16 lane)
__global__ __launch_bounds__(256) void k_agg(
    const int* __restrict__ rowptr, const int* __restrict__ deg,
    const uint2* __restrict__ spcsr, const unsigned short* __restrict__ xs16,
    const float* __restrict__ bias, unsigned short* __restrict__ xb16)
{
  const int lane = threadIdx.x & 63;
  const int grp = lane >> 4, l16 = lane & 15;
  const int node = (blockIdx.x * 256 + threadIdx.x) >> 6;
  if (node >= NN) return;
  const int base = rowptr[node];
  const int dg = deg[node];

  float acc0 = 0.f, acc1 = 0.f, acc2 = 0.f, acc3 = 0.f, psum = 0.f;
  #pragma unroll 2
  for (int e = grp; e < dg; e += 4) {
    const uint2 sp = spcsr[base + e];            // broadcast within group
    const float pv = __uint_as_float(sp.y);
    const uint2 raw = *(const uint2*)(xs16 + (size_t)sp.x*64 + l16*4);
    psum += pv;
    acc0 += pv * bflo(raw.x);
    acc1 += pv * bfhi(raw.x);
    acc2 += pv * bflo(raw.y);
    acc3 += pv * bfhi(raw.y);
  }
  // reduce across the 4 edge-groups
  #pragma unroll
  for (int off = 16; off < 64; off <<= 1) {
    acc0 += __shfl_xor(acc0, off);
    acc1 += __shfl_xor(acc1, off);
    acc2 += __shfl_xor(acc2, off);
    acc3 += __shfl_xor(acc3, off);
    psum += __shfl_xor(psum, off);
  }
  if (lane < 16) {
    const float invz = 1.f / (psum + 1e-16f);
    ushort4 w;
    w.x = f2bf(tanhf(acc0 * invz + bias[l16*4 + 0]));
    w.y = f2bf(tanhf(acc1 * invz + bias[l16*4 + 1]));
    w.z = f2bf(tanhf(acc2 * invz + bias[l16*4 + 2]));
    w.w = f2bf(tanhf(acc3 * invz + bias[l16*4 + 3]));
    *(ushort4*)(xb16 + (size_t)node*64 + l16*4) = w;
  }
}

// ---------------- K6: LSTM gates via bf16 MFMA + fused elementwise ---------
__global__ __launch_bounds__(256) void k_lstm(
    const unsigned short* __restrict__ xb16, const float* __restrict__ h0,
    const float* __restrict__ c0, const float* __restrict__ Wih,
    const float* __restrict__ Whh, float* __restrict__ out)
{
  __shared__ float gates[16][256];
  const int lane = threadIdx.x & 63;
  const int wave = threadIdx.x >> 6;     // gate quarter
  const int m = lane & 15, quad = lane >> 4;

  // B-frags: Wcat[g][k], g = wave*64 + nt*16 + m, k = kf*32 + quad*8 + j
  bf16x8 bfrag[4][4];
  #pragma unroll
  for (int nt = 0; nt < 4; ++nt) {
    const int g = wave*64 + nt*16 + m;
    #pragma unroll
    for (int kf = 0; kf < 4; ++kf) {
      const float* sp = (kf < 2) ? (Wih + g*64 + kf*32 + quad*8)
                                 : (Whh + g*64 + (kf - 2)*32 + quad*8);
      bfrag[nt][kf] = cvt8(*(const float4*)sp, *(const float4*)(sp + 4));
    }
  }

  for (int tile = blockIdx.x; tile < NN/16; tile += gridDim.x) {
    const int nodeb = tile * 16;
    bf16x8 afrag[4];
    afrag[0] = *(const bf16x8*)(xb16 + (nodeb + m)*64 + quad*8);
    afrag[1] = *(const bf16x8*)(xb16 + (nodeb + m)*64 + 32 + quad*8);
    #pragma unroll
    for (int kf = 2; kf < 4; ++kf) {
      const float* sp = h0 + (nodeb + m)*64 + (kf - 2)*32 + quad*8;
      afrag[kf] = cvt8(*(const float4*)sp, *(const float4*)(sp + 4));
    }

    f32x4 acc[4];
    #pragma unroll
    for (int nt = 0; nt < 4; ++nt) acc[nt] = f32x4{0.f, 0.f, 0.f, 0.f};
    #pragma unroll
    for (int nt = 0; nt < 4; ++nt)
      #pragma unroll
      for (int kf = 0; kf < 4; ++kf)
        acc[nt] = __builtin_amdgcn_mfma_f32_16x16x32_bf16(
            afrag[kf], bfrag[nt][kf], acc[nt], 0, 0, 0);

    #pragma unroll
    for (int nt = 0; nt < 4; ++nt)
      #pragma unroll
      for (int r = 0; r < 4; ++r)
        gates[quad*4 + r][wave*64 + nt*16 + m] = acc[nt][r];
    __syncthreads();

    const int hcol = threadIdx.x & 63;
    #pragma unroll
    for (int it = 0; it < 4; ++it) {
      const int nl = (threadIdx.x >> 6) + it*4;
      const int node = nodeb + nl;
      const float gi = gates[nl][hcol];
      const float gf = gates[nl][64 + hcol];
      const float gg = gates[nl][128 + hcol];
      const float go = gates[nl][192 + hcol];
      const float cv = c0[node*64 + hcol];
      const float c1 = sigmoidf_(gf)*cv + sigmoidf_(gi)*tanhf(gg);
      const float h1 = sigmoidf_(go)*tanhf(c1);
      out[node*64 + hcol] = h1;
      out[NN*64 + node*64 + hcol] = h1;
      out[2*NN*64 + node*64 + hcol] = c1;
    }
    __syncthreads();
  }
}

// ---------------- launch ---------------------------------------------------
extern "C" void kernel_launch(void* const* d_in, const int* in_sizes, int n_in,
                              void* d_out, int out_size, void* d_ws, size_t ws_size,
                              hipStream_t stream) {
  const float* x    = (const float*)d_in[0];
  const int*   ei   = (const int*)d_in[1];
  const float* h    = (const float*)d_in[2];
  const float* c    = (const float*)d_in[3];
  const float* Wg   = (const float*)d_in[4];
  const float* atts = (const float*)d_in[5];
  const float* attd = (const float*)d_in[6];
  const float* bg   = (const float*)d_in[7];
  const float* Wih  = (const float*)d_in[8];
  const float* Whh  = (const float*)d_in[9];
  float* out = (float*)d_out;

  char* w = (char*)d_ws;
  unsigned short* xs16 = (unsigned short*)w; w += (size_t)NN*64*2;
  unsigned short* xb16 = (unsigned short*)w; w += (size_t)NN*64*2;
  uint2* spcsr = (uint2*)w; w += (size_t)EE*8;
  float* a_src = (float*)w; w += (size_t)NN*4;
  float* a_dst = (float*)w; w += (size_t)NN*4;
  int* deg    = (int*)w; w += (size_t)NN*4;
  int* fill   = (int*)w; w += (size_t)NN*4;   // adjacent to deg: one memset
  int* rowptr = (int*)w; w += (size_t)NN*4;
  int* bsums  = (int*)w; w += 128*4;
  int* boffs  = (int*)w; w += 128*4;

  hipMemsetAsync(deg, 0, (size_t)2*NN*4, stream);   // deg + fill

  k_proj   <<<(NN/16 + 3)/4, 256, 0, stream>>>(x, Wg, atts, attd, xs16, a_src, a_dst);
  k_deg    <<<EE/256, 256, 0, stream>>>(ei, deg);
  k_scan_a <<<(NN + 1023)/1024, 256, 0, stream>>>(deg, bsums);
  k_scan_b <<<1, 128, 0, stream>>>(bsums, boffs, (NN + 1023)/1024);
  k_scan_c <<<(NN + 1023)/1024, 256, 0, stream>>>(deg, boffs, rowptr);
  k_scatter<<<EE/256, 256, 0, stream>>>(ei, a_src, a_dst, rowptr, fill, spcsr);
  k_agg    <<<NN/4, 256, 0, stream>>>(rowptr, deg, spcsr, xs16, bg, xb16);
  k_lstm   <<<1250, 256, 0, stream>>>(xb16, h, c, Wih, Whh, out);
}